// Round 1
// baseline (962.201 us; speedup 1.0000x reference)
//
#include <hip/hip_runtime.h>
#include <hip/hip_bf16.h>

#define F_IN 256
#define HDIM 128
#define CDIM 16

typedef unsigned short u16;
typedef unsigned int u32;

__device__ __forceinline__ float bf2f(u32 v) {
    u32 u = v << 16;
    float f;
    __builtin_memcpy(&f, &u, 4);
    return f;
}
__device__ __forceinline__ u16 f2bf(float f) {
    u32 u;
    __builtin_memcpy(&u, &f, 4);
    u32 r = (u + 0x7FFFu + ((u >> 16) & 1u)) >> 16;
    return (u16)r;
}
__device__ __forceinline__ u32 pack2(float lo, float hi) {
    return ((u32)f2bf(hi) << 16) | (u32)f2bf(lo);
}

// ---------------- K1: dinv[r] = rsqrt(sum_e ew[e]) ----------------
__global__ void k_dinv(const float* __restrict__ ew, const int* __restrict__ rowptr,
                       float* __restrict__ dinv, int n) {
    int r = blockIdx.x * blockDim.x + threadIdx.x;
    if (r >= n) return;
    int s = rowptr[r], e = rowptr[r + 1];
    float acc = 0.f;
    for (int i = s; i < e; i++) acc += ew[i];
    dinv[r] = (acc > 0.f) ? rsqrtf(acc) : 0.f;
}

// ---------------- K2: w[e] = dinv[row]*ew[e]*dinv[col[e]] ----------------
__global__ void k_w(const float* __restrict__ ew, const int* __restrict__ rowptr,
                    const int* __restrict__ col, const float* __restrict__ dinv,
                    float* __restrict__ wn, int n) {
    int r = blockIdx.x * blockDim.x + threadIdx.x;
    if (r >= n) return;
    float dr = dinv[r];
    int s = rowptr[r], e = rowptr[r + 1];
    for (int i = s; i < e; i++) wn[i] = dr * ew[i] * dinv[col[i]];
}

// ---------------- K3: T1 = x @ W1  (fp32 in, bf16 out) ----------------
// block = 256 threads: 32 rows x 8 f-groups (16 outputs each)
__global__ __launch_bounds__(256) void k_gemm1(const float* __restrict__ x,
                                               const float* __restrict__ W1,
                                               u16* __restrict__ T1, int n) {
    int rl = threadIdx.x >> 3;          // 0..31
    int f0 = (threadIdx.x & 7) * 16;    // 0,16,...,112
    int row = blockIdx.x * 32 + rl;
    if (row >= n) return;

    const float4* xr4 = (const float4*)(x + (size_t)row * F_IN);
    float4 a0 = {0, 0, 0, 0}, a1 = {0, 0, 0, 0}, a2 = {0, 0, 0, 0}, a3 = {0, 0, 0, 0};

    for (int k4 = 0; k4 < F_IN / 4; k4++) {
        float4 xv = xr4[k4];
        const float* Wb = W1 + (size_t)(k4 * 4) * HDIM + f0;
#pragma unroll
        for (int kk = 0; kk < 4; kk++) {
            float xs = (kk == 0) ? xv.x : (kk == 1) ? xv.y : (kk == 2) ? xv.z : xv.w;
            const float4* wr = (const float4*)(Wb + (size_t)kk * HDIM);
            float4 w0 = wr[0], w1 = wr[1], w2 = wr[2], w3 = wr[3];
            a0.x += xs * w0.x; a0.y += xs * w0.y; a0.z += xs * w0.z; a0.w += xs * w0.w;
            a1.x += xs * w1.x; a1.y += xs * w1.y; a1.z += xs * w1.z; a1.w += xs * w1.w;
            a2.x += xs * w2.x; a2.y += xs * w2.y; a2.z += xs * w2.z; a2.w += xs * w2.w;
            a3.x += xs * w3.x; a3.y += xs * w3.y; a3.z += xs * w3.z; a3.w += xs * w3.w;
        }
    }

    uint4 o0, o1;
    o0.x = pack2(a0.x, a0.y); o0.y = pack2(a0.z, a0.w);
    o0.z = pack2(a1.x, a1.y); o0.w = pack2(a1.z, a1.w);
    o1.x = pack2(a2.x, a2.y); o1.y = pack2(a2.z, a2.w);
    o1.z = pack2(a3.x, a3.y); o1.w = pack2(a3.z, a3.w);
    uint4* op = (uint4*)(T1 + (size_t)row * HDIM + f0);
    op[0] = o0;
    op[1] = o1;
}

// ---------------- K4: H = relu(SpMM(T1) + b1)  (bf16 in/out) ----------------
// one wave per row, lane owns 2 consecutive features
__global__ __launch_bounds__(64) void k_spmm1(const u16* __restrict__ T1,
                                              const float* __restrict__ wn,
                                              const int* __restrict__ rowptr,
                                              const int* __restrict__ col,
                                              const float* __restrict__ b1,
                                              u16* __restrict__ H, int n) {
    int r = blockIdx.x;
    int lane = threadIdx.x;
    int f2 = lane * 2;
    int s = rowptr[r], e = rowptr[r + 1];
    float a0 = 0.f, a1 = 0.f;
    for (int i = s; i < e; i++) {
        float we = wn[i];
        int c = col[i];
        u32 pr = *(const u32*)(T1 + (size_t)c * HDIM + f2);
        a0 += we * bf2f(pr & 0xFFFFu);
        a1 += we * bf2f(pr >> 16);
    }
    float v0 = a0 + b1[f2];
    float v1 = a1 + b1[f2 + 1];
    v0 = v0 > 0.f ? v0 : 0.f;
    v1 = v1 > 0.f ? v1 : 0.f;
    *(u32*)(H + (size_t)r * HDIM + f2) = pack2(v0, v1);
}

// ---------------- K5: U = H @ W2  (bf16 in, f32 out) ----------------
// block = 256: 16 rows x 16 features
__global__ __launch_bounds__(256) void k_gemm2(const u16* __restrict__ H,
                                               const float* __restrict__ W2,
                                               float* __restrict__ U, int n) {
    int rl = threadIdx.x >> 4;
    int f = threadIdx.x & 15;
    int row = blockIdx.x * 16 + rl;
    if (row >= n) return;
    const u32* hr = (const u32*)(H + (size_t)row * HDIM);
    float acc = 0.f;
    for (int k2 = 0; k2 < HDIM / 2; k2++) {
        u32 pr = hr[k2];
        float h0 = bf2f(pr & 0xFFFFu);
        float h1 = bf2f(pr >> 16);
        acc += h0 * W2[(size_t)(k2 * 2) * CDIM + f];
        acc += h1 * W2[(size_t)(k2 * 2 + 1) * CDIM + f];
    }
    U[(size_t)row * CDIM + f] = acc;
}

// ---------------- K6: out = log_softmax(SpMM(U) + b2) ----------------
// one wave per row: 4 parallel edges x 16 features
__global__ __launch_bounds__(64) void k_out(const float* __restrict__ U,
                                            const float* __restrict__ wn,
                                            const int* __restrict__ rowptr,
                                            const int* __restrict__ col,
                                            const float* __restrict__ b2,
                                            float* __restrict__ out, int n) {
    int r = blockIdx.x;
    int lane = threadIdx.x;
    int es = lane >> 4;   // 0..3
    int f = lane & 15;
    int s = rowptr[r], e = rowptr[r + 1];
    float acc = 0.f;
    for (int i = s + es; i < e; i += 4) {
        float we = wn[i];
        int c = col[i];
        acc += we * U[(size_t)c * CDIM + f];
    }
    // reduce across the 4 edge sub-groups
    acc += __shfl_xor(acc, 16);
    acc += __shfl_xor(acc, 32);
    float v = acc + b2[f];
    // log-softmax over 16 lanes
    float m = v;
    for (int d = 1; d < 16; d <<= 1) m = fmaxf(m, __shfl_xor(m, d));
    float ex = __expf(v - m);
    float ss = ex;
    for (int d = 1; d < 16; d <<= 1) ss += __shfl_xor(ss, d);
    float res = v - m - __logf(ss);
    if (lane < 16) out[(size_t)r * CDIM + f] = res;
}

extern "C" void kernel_launch(void* const* d_in, const int* in_sizes, int n_in,
                              void* d_out, int out_size, void* d_ws, size_t ws_size,
                              hipStream_t stream) {
    const float* x      = (const float*)d_in[0];
    const float* ew     = (const float*)d_in[1];
    const float* W1     = (const float*)d_in[2];
    const float* b1     = (const float*)d_in[3];
    const float* W2     = (const float*)d_in[4];
    const float* b2     = (const float*)d_in[5];
    const int*   rowptr = (const int*)d_in[6];
    const int*   colind = (const int*)d_in[7];

    int n = in_sizes[6] - 1;   // rowptr has n+1 entries
    int E = in_sizes[7];

    auto align256 = [](size_t v) { return (v + 255) & ~(size_t)255; };
    char* p = (char*)d_ws;
    float* dinv = (float*)p; p += align256((size_t)n * 4);
    float* wn   = (float*)p; p += align256((size_t)E * 4);
    u16*   T1   = (u16*)p;   p += align256((size_t)n * HDIM * 2);
    u16*   H    = (u16*)p;   p += align256((size_t)n * HDIM * 2);
    float* U    = (float*)p; p += align256((size_t)n * CDIM * 4);
    float* out  = (float*)d_out;

    k_dinv<<<(n + 255) / 256, 256, 0, stream>>>(ew, rowptr, dinv, n);
    k_w<<<(n + 255) / 256, 256, 0, stream>>>(ew, rowptr, colind, dinv, wn, n);
    k_gemm1<<<(n + 31) / 32, 256, 0, stream>>>(x, W1, T1, n);
    k_spmm1<<<n, 64, 0, stream>>>(T1, wn, rowptr, colind, b1, H, n);
    k_gemm2<<<(n + 15) / 16, 256, 0, stream>>>(H, W2, U, n);
    k_out<<<n, 64, 0, stream>>>(U, wn, rowptr, colind, b2, out, n);
}

// Round 2
// 283.652 us; speedup vs baseline: 3.3922x; 3.3922x over previous
//
#include <hip/hip_runtime.h>
#include <hip/hip_bf16.h>

#define F_IN 256
#define HDIM 128
#define CDIM 16

typedef unsigned short u16;
typedef unsigned int u32;

typedef __attribute__((ext_vector_type(8))) short bf16x8;
typedef __attribute__((ext_vector_type(4))) float f32x4;

__device__ __forceinline__ float bf2f(u32 v) {
    u32 u = v << 16;
    float f;
    __builtin_memcpy(&f, &u, 4);
    return f;
}
__device__ __forceinline__ u16 f2bf(float f) {
    u32 u;
    __builtin_memcpy(&u, &f, 4);
    u32 r = (u + 0x7FFFu + ((u >> 16) & 1u)) >> 16;
    return (u16)r;
}
__device__ __forceinline__ u32 pack2(float lo, float hi) {
    return ((u32)f2bf(hi) << 16) | (u32)f2bf(lo);
}

// ---------------- K1: dinv[r] = rsqrt(sum_e ew[e]) ----------------
__global__ void k_dinv(const float* __restrict__ ew, const int* __restrict__ rowptr,
                       float* __restrict__ dinv, int n) {
    int r = blockIdx.x * blockDim.x + threadIdx.x;
    if (r >= n) return;
    int s = rowptr[r], e = rowptr[r + 1];
    float acc = 0.f;
    for (int i = s; i < e; i++) acc += ew[i];
    dinv[r] = (acc > 0.f) ? rsqrtf(acc) : 0.f;
}

// ---------------- K2: w[e] = dinv[row]*ew[e]*dinv[col[e]] ----------------
__global__ void k_w(const float* __restrict__ ew, const int* __restrict__ rowptr,
                    const int* __restrict__ col, const float* __restrict__ dinv,
                    float* __restrict__ wn, int n) {
    int r = blockIdx.x * blockDim.x + threadIdx.x;
    if (r >= n) return;
    float dr = dinv[r];
    int s = rowptr[r], e = rowptr[r + 1];
    for (int i = s; i < e; i++) wn[i] = dr * ew[i] * dinv[col[i]];
}

// ---------------- K-prep: W1T[f][k] = bf16(W1[k][f])  (128x256 bf16) ----------------
__global__ void k_prepw1(const float* __restrict__ W1, u16* __restrict__ W1T) {
    int idx = blockIdx.x * blockDim.x + threadIdx.x;   // 0..32767
    if (idx >= HDIM * F_IN) return;
    int f = idx >> 8;         // 0..127
    int k = idx & 255;        // 0..255
    W1T[idx] = f2bf(W1[(size_t)k * HDIM + f]);
}

// ---------------- K3: T1 = x @ W1 via bf16 MFMA (fp32 x converted in-reg) ----------
// 4 waves/block; each wave computes a 16-row x 128-col tile.
// A-frag: lane reads x[r0 + (lane&15)][kk*32 + (lane>>4)*8 .. +8] (2x float4 -> bf16)
// B-frag: lane reads W1T[ct*16 + (lane&15)][kk*32 + (lane>>4)*8 .. +8] (bf16x8)
// D: col = lane&15, row = (lane>>4)*4 + reg   [m89-verified]
__global__ __launch_bounds__(256) void k_gemm1(const float* __restrict__ x,
                                               const u16* __restrict__ W1T,
                                               u16* __restrict__ T1, int n) {
    int wave = threadIdx.x >> 6;
    int lane = threadIdx.x & 63;
    int tile = blockIdx.x * 4 + wave;
    int r0 = tile * 16;
    if (r0 >= n) return;

    int lr = lane & 15;          // row within tile (A) / col within tile (B)
    int kg = lane >> 4;          // k-group 0..3

    f32x4 acc[8];
#pragma unroll
    for (int i = 0; i < 8; i++) acc[i] = (f32x4){0.f, 0.f, 0.f, 0.f};

    const float* arow = x + (size_t)(r0 + lr) * F_IN + kg * 8;

#pragma unroll
    for (int kk = 0; kk < F_IN / 32; kk++) {
        // --- A fragment: 8 contiguous k as bf16 ---
        const float4* ap = (const float4*)(arow + kk * 32);
        float4 alo = ap[0];
        float4 ahi = ap[1];
        bf16x8 afrag;
        afrag[0] = (short)f2bf(alo.x); afrag[1] = (short)f2bf(alo.y);
        afrag[2] = (short)f2bf(alo.z); afrag[3] = (short)f2bf(alo.w);
        afrag[4] = (short)f2bf(ahi.x); afrag[5] = (short)f2bf(ahi.y);
        afrag[6] = (short)f2bf(ahi.z); afrag[7] = (short)f2bf(ahi.w);

        const u16* bbase = W1T + (size_t)lr * F_IN + kg * 8 + kk * 32;
#pragma unroll
        for (int ct = 0; ct < 8; ct++) {
            bf16x8 bfrag = *(const bf16x8*)(bbase + (size_t)ct * 16 * F_IN);
            acc[ct] = __builtin_amdgcn_mfma_f32_16x16x32_bf16(afrag, bfrag, acc[ct], 0, 0, 0);
        }
    }

    // --- store: T1[r0 + kg*4 + i][ct*16 + lr] ---
#pragma unroll
    for (int ct = 0; ct < 8; ct++) {
        u16* op = T1 + (size_t)(r0 + kg * 4) * HDIM + ct * 16 + lr;
#pragma unroll
        for (int i = 0; i < 4; i++) {
            op[(size_t)i * HDIM] = f2bf(acc[ct][i]);
        }
    }
}

// ---------------- K4: H = relu(SpMM(T1) + b1)  (bf16 in/out) ----------------
// one wave per row, lane owns 2 consecutive features
__global__ __launch_bounds__(64) void k_spmm1(const u16* __restrict__ T1,
                                              const float* __restrict__ wn,
                                              const int* __restrict__ rowptr,
                                              const int* __restrict__ col,
                                              const float* __restrict__ b1,
                                              u16* __restrict__ H, int n) {
    int r = blockIdx.x;
    int lane = threadIdx.x;
    int f2 = lane * 2;
    int s = rowptr[r], e = rowptr[r + 1];
    float a0 = 0.f, a1 = 0.f;
    for (int i = s; i < e; i++) {
        float we = wn[i];
        int c = col[i];
        u32 pr = *(const u32*)(T1 + (size_t)c * HDIM + f2);
        a0 += we * bf2f(pr & 0xFFFFu);
        a1 += we * bf2f(pr >> 16);
    }
    float v0 = a0 + b1[f2];
    float v1 = a1 + b1[f2 + 1];
    v0 = v0 > 0.f ? v0 : 0.f;
    v1 = v1 > 0.f ? v1 : 0.f;
    *(u32*)(H + (size_t)r * HDIM + f2) = pack2(v0, v1);
}

// ---------------- K5: U = H @ W2  (bf16 in, f32 out) ----------------
// block = 256: 16 rows x 16 features
__global__ __launch_bounds__(256) void k_gemm2(const u16* __restrict__ H,
                                               const float* __restrict__ W2,
                                               float* __restrict__ U, int n) {
    int rl = threadIdx.x >> 4;
    int f = threadIdx.x & 15;
    int row = blockIdx.x * 16 + rl;
    if (row >= n) return;
    const u32* hr = (const u32*)(H + (size_t)row * HDIM);
    float acc = 0.f;
    for (int k2 = 0; k2 < HDIM / 2; k2++) {
        u32 pr = hr[k2];
        float h0 = bf2f(pr & 0xFFFFu);
        float h1 = bf2f(pr >> 16);
        acc += h0 * W2[(size_t)(k2 * 2) * CDIM + f];
        acc += h1 * W2[(size_t)(k2 * 2 + 1) * CDIM + f];
    }
    U[(size_t)row * CDIM + f] = acc;
}

// ---------------- K6: out = log_softmax(SpMM(U) + b2) ----------------
// one wave per row: 4 parallel edges x 16 features
__global__ __launch_bounds__(64) void k_out(const float* __restrict__ U,
                                            const float* __restrict__ wn,
                                            const int* __restrict__ rowptr,
                                            const int* __restrict__ col,
                                            const float* __restrict__ b2,
                                            float* __restrict__ out, int n) {
    int r = blockIdx.x;
    int lane = threadIdx.x;
    int es = lane >> 4;   // 0..3
    int f = lane & 15;
    int s = rowptr[r], e = rowptr[r + 1];
    float acc = 0.f;
    for (int i = s + es; i < e; i += 4) {
        float we = wn[i];
        int c = col[i];
        acc += we * U[(size_t)c * CDIM + f];
    }
    // reduce across the 4 edge sub-groups
    acc += __shfl_xor(acc, 16);
    acc += __shfl_xor(acc, 32);
    float v = acc + b2[f];
    // log-softmax over 16 lanes
    float m = v;
    for (int d = 1; d < 16; d <<= 1) m = fmaxf(m, __shfl_xor(m, d));
    float ex = __expf(v - m);
    float ss = ex;
    for (int d = 1; d < 16; d <<= 1) ss += __shfl_xor(ss, d);
    float res = v - m - __logf(ss);
    if (lane < 16) out[(size_t)r * CDIM + f] = res;
}

extern "C" void kernel_launch(void* const* d_in, const int* in_sizes, int n_in,
                              void* d_out, int out_size, void* d_ws, size_t ws_size,
                              hipStream_t stream) {
    const float* x      = (const float*)d_in[0];
    const float* ew     = (const float*)d_in[1];
    const float* W1     = (const float*)d_in[2];
    const float* b1     = (const float*)d_in[3];
    const float* W2     = (const float*)d_in[4];
    const float* b2     = (const float*)d_in[5];
    const int*   rowptr = (const int*)d_in[6];
    const int*   colind = (const int*)d_in[7];

    int n = in_sizes[6] - 1;   // rowptr has n+1 entries
    int E = in_sizes[7];

    auto align256 = [](size_t v) { return (v + 255) & ~(size_t)255; };
    char* p = (char*)d_ws;
    float* dinv = (float*)p; p += align256((size_t)n * 4);
    float* wn   = (float*)p; p += align256((size_t)E * 4);
    u16*   T1   = (u16*)p;   p += align256((size_t)n * HDIM * 2);
    u16*   H    = (u16*)p;   p += align256((size_t)n * HDIM * 2);
    float* U    = (float*)p; p += align256((size_t)n * CDIM * 4);
    u16*   W1T  = (u16*)p;   p += align256((size_t)HDIM * F_IN * 2);
    float* out  = (float*)d_out;

    k_dinv<<<(n + 255) / 256, 256, 0, stream>>>(ew, rowptr, dinv, n);
    k_w<<<(n + 255) / 256, 256, 0, stream>>>(ew, rowptr, colind, dinv, wn, n);
    k_prepw1<<<(HDIM * F_IN + 255) / 256, 256, 0, stream>>>(W1, W1T);

    int tiles = (n + 15) / 16;
    k_gemm1<<<(tiles + 3) / 4, 256, 0, stream>>>(x, W1T, T1, n);

    k_spmm1<<<n, 64, 0, stream>>>(T1, wn, rowptr, colind, b1, H, n);
    k_gemm2<<<(n + 15) / 16, 256, 0, stream>>>(H, W2, U, n);
    k_out<<<n, 64, 0, stream>>>(U, wn, rowptr, colind, b2, out, n);
}

// Round 3
// 240.207 us; speedup vs baseline: 4.0057x; 1.1809x over previous
//
#include <hip/hip_runtime.h>
#include <hip/hip_bf16.h>

#define F_IN 256
#define HDIM 128
#define CDIM 16

typedef unsigned short u16;
typedef unsigned int u32;

typedef __attribute__((ext_vector_type(8))) short bf16x8;
typedef __attribute__((ext_vector_type(4))) float f32x4;

__device__ __forceinline__ float bf2f(u32 v) {
    u32 u = v << 16;
    float f;
    __builtin_memcpy(&f, &u, 4);
    return f;
}
__device__ __forceinline__ u16 f2bf(float f) {
    u32 u;
    __builtin_memcpy(&u, &f, 4);
    u32 r = (u + 0x7FFFu + ((u >> 16) & 1u)) >> 16;
    return (u16)r;
}
__device__ __forceinline__ u32 pack2(float lo, float hi) {
    return ((u32)f2bf(hi) << 16) | (u32)f2bf(lo);
}

// ---------------- K1: dinv[r] = rsqrt(sum_e ew[e]) ----------------
__global__ void k_dinv(const float* __restrict__ ew, const int* __restrict__ rowptr,
                       float* __restrict__ dinv, int n) {
    int r = blockIdx.x * blockDim.x + threadIdx.x;
    if (r >= n) return;
    int s = rowptr[r], e = rowptr[r + 1];
    float acc = 0.f;
    for (int i = s; i < e; i++) acc += ew[i];
    dinv[r] = (acc > 0.f) ? rsqrtf(acc) : 0.f;
}

// ---------------- K2: w[e] = dinv[row]*ew[e]*dinv[col[e]] ----------------
__global__ void k_w(const float* __restrict__ ew, const int* __restrict__ rowptr,
                    const int* __restrict__ col, const float* __restrict__ dinv,
                    float* __restrict__ wn, int n) {
    int r = blockIdx.x * blockDim.x + threadIdx.x;
    if (r >= n) return;
    float dr = dinv[r];
    int s = rowptr[r], e = rowptr[r + 1];
    for (int i = s; i < e; i++) wn[i] = dr * ew[i] * dinv[col[i]];
}

// ---------------- K-prep: W1T[f][k] = bf16(W1[k][f])  (128x256 bf16) ----------------
__global__ void k_prepw1(const float* __restrict__ W1, u16* __restrict__ W1T) {
    int idx = blockIdx.x * blockDim.x + threadIdx.x;   // 0..32767
    if (idx >= HDIM * F_IN) return;
    int f = idx >> 8;         // 0..127
    int k = idx & 255;        // 0..255
    W1T[idx] = f2bf(W1[(size_t)k * HDIM + f]);
}

// ---------------- K3: T1 = x @ W1 via bf16 MFMA (fp32 x converted in-reg) ----------
__global__ __launch_bounds__(256) void k_gemm1(const float* __restrict__ x,
                                               const u16* __restrict__ W1T,
                                               u16* __restrict__ T1, int n) {
    int wave = threadIdx.x >> 6;
    int lane = threadIdx.x & 63;
    int tile = blockIdx.x * 4 + wave;
    int r0 = tile * 16;
    if (r0 >= n) return;

    int lr = lane & 15;          // row within tile (A) / col within tile (B)
    int kg = lane >> 4;          // k-group 0..3

    f32x4 acc[8];
#pragma unroll
    for (int i = 0; i < 8; i++) acc[i] = (f32x4){0.f, 0.f, 0.f, 0.f};

    const float* arow = x + (size_t)(r0 + lr) * F_IN + kg * 8;

#pragma unroll
    for (int kk = 0; kk < F_IN / 32; kk++) {
        const float4* ap = (const float4*)(arow + kk * 32);
        float4 alo = ap[0];
        float4 ahi = ap[1];
        bf16x8 afrag;
        afrag[0] = (short)f2bf(alo.x); afrag[1] = (short)f2bf(alo.y);
        afrag[2] = (short)f2bf(alo.z); afrag[3] = (short)f2bf(alo.w);
        afrag[4] = (short)f2bf(ahi.x); afrag[5] = (short)f2bf(ahi.y);
        afrag[6] = (short)f2bf(ahi.z); afrag[7] = (short)f2bf(ahi.w);

        const u16* bbase = W1T + (size_t)lr * F_IN + kg * 8 + kk * 32;
#pragma unroll
        for (int ct = 0; ct < 8; ct++) {
            bf16x8 bfrag = *(const bf16x8*)(bbase + (size_t)ct * 16 * F_IN);
            acc[ct] = __builtin_amdgcn_mfma_f32_16x16x32_bf16(afrag, bfrag, acc[ct], 0, 0, 0);
        }
    }

#pragma unroll
    for (int ct = 0; ct < 8; ct++) {
        u16* op = T1 + (size_t)(r0 + kg * 4) * HDIM + ct * 16 + lr;
#pragma unroll
        for (int i = 0; i < 4; i++) {
            op[(size_t)i * HDIM] = f2bf(acc[ct][i]);
        }
    }
}

// ---------------- K4: H = relu(SpMM(T1) + b1)  (bf16 in/out) ----------------
// 4 waves/block, 1 row/wave. Wave = 4x 16-lane subgroups, each owns one edge.
// Lane gathers 16B (8 bf16 features). x2 unroll -> 8 outstanding gathers/wave.
__global__ __launch_bounds__(256) void k_spmm1(const u16* __restrict__ T1,
                                               const float* __restrict__ wn,
                                               const int* __restrict__ rowptr,
                                               const int* __restrict__ col,
                                               const float* __restrict__ b1,
                                               u16* __restrict__ H, int n) {
    int wave = threadIdx.x >> 6;
    int lane = threadIdx.x & 63;
    int r = blockIdx.x * 4 + wave;
    if (r >= n) return;
    int es = lane >> 4;          // subgroup 0..3 (edge slot)
    int fl = lane & 15;          // feature group: features fl*8 .. fl*8+7

    int s = rowptr[r], e = rowptr[r + 1];
    float a[8];
#pragma unroll
    for (int j = 0; j < 8; j++) a[j] = 0.f;

    int i = s + es;
    for (; i + 4 < e; i += 8) {
        float w0 = wn[i];
        int c0 = col[i];
        float w1 = wn[i + 4];
        int c1 = col[i + 4];
        uint4 p0 = *(const uint4*)(T1 + (size_t)c0 * HDIM + fl * 8);
        uint4 p1 = *(const uint4*)(T1 + (size_t)c1 * HDIM + fl * 8);
        a[0] += w0 * bf2f(p0.x & 0xFFFFu); a[1] += w0 * bf2f(p0.x >> 16);
        a[2] += w0 * bf2f(p0.y & 0xFFFFu); a[3] += w0 * bf2f(p0.y >> 16);
        a[4] += w0 * bf2f(p0.z & 0xFFFFu); a[5] += w0 * bf2f(p0.z >> 16);
        a[6] += w0 * bf2f(p0.w & 0xFFFFu); a[7] += w0 * bf2f(p0.w >> 16);
        a[0] += w1 * bf2f(p1.x & 0xFFFFu); a[1] += w1 * bf2f(p1.x >> 16);
        a[2] += w1 * bf2f(p1.y & 0xFFFFu); a[3] += w1 * bf2f(p1.y >> 16);
        a[4] += w1 * bf2f(p1.z & 0xFFFFu); a[5] += w1 * bf2f(p1.z >> 16);
        a[6] += w1 * bf2f(p1.w & 0xFFFFu); a[7] += w1 * bf2f(p1.w >> 16);
    }
    if (i < e) {
        float w0 = wn[i];
        int c0 = col[i];
        uint4 p0 = *(const uint4*)(T1 + (size_t)c0 * HDIM + fl * 8);
        a[0] += w0 * bf2f(p0.x & 0xFFFFu); a[1] += w0 * bf2f(p0.x >> 16);
        a[2] += w0 * bf2f(p0.y & 0xFFFFu); a[3] += w0 * bf2f(p0.y >> 16);
        a[4] += w0 * bf2f(p0.z & 0xFFFFu); a[5] += w0 * bf2f(p0.z >> 16);
        a[6] += w0 * bf2f(p0.w & 0xFFFFu); a[7] += w0 * bf2f(p0.w >> 16);
    }

    // reduce across the 4 edge subgroups
#pragma unroll
    for (int j = 0; j < 8; j++) {
        a[j] += __shfl_xor(a[j], 16);
        a[j] += __shfl_xor(a[j], 32);
    }

    if (es == 0) {
        const float4* bb = (const float4*)(b1 + fl * 8);
        float4 blo = bb[0], bhi = bb[1];
        float v0 = a[0] + blo.x, v1 = a[1] + blo.y;
        float v2 = a[2] + blo.z, v3 = a[3] + blo.w;
        float v4 = a[4] + bhi.x, v5 = a[5] + bhi.y;
        float v6 = a[6] + bhi.z, v7 = a[7] + bhi.w;
        v0 = v0 > 0.f ? v0 : 0.f; v1 = v1 > 0.f ? v1 : 0.f;
        v2 = v2 > 0.f ? v2 : 0.f; v3 = v3 > 0.f ? v3 : 0.f;
        v4 = v4 > 0.f ? v4 : 0.f; v5 = v5 > 0.f ? v5 : 0.f;
        v6 = v6 > 0.f ? v6 : 0.f; v7 = v7 > 0.f ? v7 : 0.f;
        uint4 o;
        o.x = pack2(v0, v1); o.y = pack2(v2, v3);
        o.z = pack2(v4, v5); o.w = pack2(v6, v7);
        *(uint4*)(H + (size_t)r * HDIM + fl * 8) = o;
    }
}

// ---------------- K5: U = H @ W2  (bf16 in, f32 out) ----------------
__global__ __launch_bounds__(256) void k_gemm2(const u16* __restrict__ H,
                                               const float* __restrict__ W2,
                                               float* __restrict__ U, int n) {
    int rl = threadIdx.x >> 4;
    int f = threadIdx.x & 15;
    int row = blockIdx.x * 16 + rl;
    if (row >= n) return;
    const u32* hr = (const u32*)(H + (size_t)row * HDIM);
    float acc = 0.f;
    for (int k2 = 0; k2 < HDIM / 2; k2++) {
        u32 pr = hr[k2];
        float h0 = bf2f(pr & 0xFFFFu);
        float h1 = bf2f(pr >> 16);
        acc += h0 * W2[(size_t)(k2 * 2) * CDIM + f];
        acc += h1 * W2[(size_t)(k2 * 2 + 1) * CDIM + f];
    }
    U[(size_t)row * CDIM + f] = acc;
}

// ---------------- K6: out = log_softmax(SpMM(U) + b2) ----------------
// 4 waves/block, 1 row/wave: 4 parallel edges x 16 features, x2 unroll
__global__ __launch_bounds__(256) void k_out(const float* __restrict__ U,
                                             const float* __restrict__ wn,
                                             const int* __restrict__ rowptr,
                                             const int* __restrict__ col,
                                             const float* __restrict__ b2,
                                             float* __restrict__ out, int n) {
    int wave = threadIdx.x >> 6;
    int lane = threadIdx.x & 63;
    int r = blockIdx.x * 4 + wave;
    if (r >= n) return;
    int es = lane >> 4;   // 0..3
    int f = lane & 15;
    int s = rowptr[r], e = rowptr[r + 1];
    float acc = 0.f;
    int i = s + es;
    for (; i + 4 < e; i += 8) {
        float w0 = wn[i];
        int c0 = col[i];
        float w1 = wn[i + 4];
        int c1 = col[i + 4];
        acc += w0 * U[(size_t)c0 * CDIM + f];
        acc += w1 * U[(size_t)c1 * CDIM + f];
    }
    if (i < e) {
        acc += wn[i] * U[(size_t)col[i] * CDIM + f];
    }
    // reduce across the 4 edge sub-groups
    acc += __shfl_xor(acc, 16);
    acc += __shfl_xor(acc, 32);
    float v = acc + b2[f];
    // log-softmax over 16 lanes
    float m = v;
    for (int d = 1; d < 16; d <<= 1) m = fmaxf(m, __shfl_xor(m, d));
    float ex = __expf(v - m);
    float ss = ex;
    for (int d = 1; d < 16; d <<= 1) ss += __shfl_xor(ss, d);
    float res = v - m - __logf(ss);
    if (es == 0) out[(size_t)r * CDIM + f] = res;
}

extern "C" void kernel_launch(void* const* d_in, const int* in_sizes, int n_in,
                              void* d_out, int out_size, void* d_ws, size_t ws_size,
                              hipStream_t stream) {
    const float* x      = (const float*)d_in[0];
    const float* ew     = (const float*)d_in[1];
    const float* W1     = (const float*)d_in[2];
    const float* b1     = (const float*)d_in[3];
    const float* W2     = (const float*)d_in[4];
    const float* b2     = (const float*)d_in[5];
    const int*   rowptr = (const int*)d_in[6];
    const int*   colind = (const int*)d_in[7];

    int n = in_sizes[6] - 1;   // rowptr has n+1 entries
    int E = in_sizes[7];

    auto align256 = [](size_t v) { return (v + 255) & ~(size_t)255; };
    char* p = (char*)d_ws;
    float* dinv = (float*)p; p += align256((size_t)n * 4);
    float* wn   = (float*)p; p += align256((size_t)E * 4);
    u16*   T1   = (u16*)p;   p += align256((size_t)n * HDIM * 2);
    u16*   H    = (u16*)p;   p += align256((size_t)n * HDIM * 2);
    float* U    = (float*)p; p += align256((size_t)n * CDIM * 4);
    u16*   W1T  = (u16*)p;   p += align256((size_t)HDIM * F_IN * 2);
    float* out  = (float*)d_out;

    k_dinv<<<(n + 255) / 256, 256, 0, stream>>>(ew, rowptr, dinv, n);
    k_w<<<(n + 255) / 256, 256, 0, stream>>>(ew, rowptr, colind, dinv, wn, n);
    k_prepw1<<<(HDIM * F_IN + 255) / 256, 256, 0, stream>>>(W1, W1T);

    int tiles = (n + 15) / 16;
    k_gemm1<<<(tiles + 3) / 4, 256, 0, stream>>>(x, W1T, T1, n);

    k_spmm1<<<(n + 3) / 4, 256, 0, stream>>>(T1, wn, rowptr, colind, b1, H, n);
    k_gemm2<<<(n + 15) / 16, 256, 0, stream>>>(H, W2, U, n);
    k_out<<<(n + 3) / 4, 256, 0, stream>>>(U, wn, rowptr, colind, b2, out, n);
}

// Round 4
// 217.325 us; speedup vs baseline: 4.4275x; 1.1053x over previous
//
#include <hip/hip_runtime.h>
#include <hip/hip_bf16.h>

#define F_IN 256
#define HDIM 128
#define CDIM 16

typedef unsigned short u16;
typedef unsigned int u32;

typedef __attribute__((ext_vector_type(8))) short bf16x8;
typedef __attribute__((ext_vector_type(4))) float f32x4;

__device__ __forceinline__ float bf2f(u32 v) {
    u32 u = v << 16;
    float f;
    __builtin_memcpy(&f, &u, 4);
    return f;
}
__device__ __forceinline__ u16 f2bf(float f) {
    u32 u;
    __builtin_memcpy(&u, &f, 4);
    u32 r = (u + 0x7FFFu + ((u >> 16) & 1u)) >> 16;
    return (u16)r;
}
__device__ __forceinline__ u32 pack2(float lo, float hi) {
    return ((u32)f2bf(hi) << 16) | (u32)f2bf(lo);
}

// ---------------- K1: dinv[r] = rsqrt(sum_e ew[e]) ----------------
__global__ void k_dinv(const float* __restrict__ ew, const int* __restrict__ rowptr,
                       float* __restrict__ dinv, int n) {
    int r = blockIdx.x * blockDim.x + threadIdx.x;
    if (r >= n) return;
    int s = rowptr[r], e = rowptr[r + 1];
    float acc = 0.f;
    for (int i = s; i < e; i++) acc += ew[i];
    dinv[r] = (acc > 0.f) ? rsqrtf(acc) : 0.f;
}

// ---------------- K2: w[e] = dinv[row]*ew[e]*dinv[col[e]] ----------------
__global__ void k_w(const float* __restrict__ ew, const int* __restrict__ rowptr,
                    const int* __restrict__ col, const float* __restrict__ dinv,
                    float* __restrict__ wn, int n) {
    int r = blockIdx.x * blockDim.x + threadIdx.x;
    if (r >= n) return;
    float dr = dinv[r];
    int s = rowptr[r], e = rowptr[r + 1];
    for (int i = s; i < e; i++) wn[i] = dr * ew[i] * dinv[col[i]];
}

// ---------------- K-prep: W1T[f][k] = bf16(W1[k][f])  (128x256 bf16) ----------------
__global__ void k_prepw1(const float* __restrict__ W1, u16* __restrict__ W1T) {
    int idx = blockIdx.x * blockDim.x + threadIdx.x;   // 0..32767
    if (idx >= HDIM * F_IN) return;
    int f = idx >> 8;         // 0..127
    int k = idx & 255;        // 0..255
    W1T[idx] = f2bf(W1[(size_t)k * HDIM + f]);
}

// ---------------- K3: T1 = x @ W1 via bf16 MFMA ----------
// 1 wave = 64-row x 128-col tile (4 row-groups of 16 share every B-fragment).
// A-frag: lane reads x[r0 + rg*16 + (lane&15)][kk*32 + (lane>>4)*8 .. +8]
// B-frag: lane reads W1T[ct*16 + (lane&15)][kk*32 + (lane>>4)*8 .. +8]
// D: col = lane&15, row = (lane>>4)*4 + reg   [m89-verified]
__global__ __launch_bounds__(256) void k_gemm1(const float* __restrict__ x,
                                               const u16* __restrict__ W1T,
                                               u16* __restrict__ T1, int n) {
    int wave = threadIdx.x >> 6;
    int lane = threadIdx.x & 63;
    int r0 = (blockIdx.x * 4 + wave) * 64;
    if (r0 >= n) return;

    int lr = lane & 15;          // row within 16-group (A) / col within 16-group (B)
    int kg = lane >> 4;          // k-group 0..3

    f32x4 acc[4][8];
#pragma unroll
    for (int rg = 0; rg < 4; rg++)
#pragma unroll
        for (int ct = 0; ct < 8; ct++) acc[rg][ct] = (f32x4){0.f, 0.f, 0.f, 0.f};

    int rowc[4];
#pragma unroll
    for (int rg = 0; rg < 4; rg++) {
        int row = r0 + rg * 16 + lr;
        rowc[rg] = row < n ? row : (n - 1);   // clamp for safe load; store is guarded
    }

#pragma unroll
    for (int kk = 0; kk < F_IN / 32; kk++) {
        bf16x8 afrag[4];
#pragma unroll
        for (int rg = 0; rg < 4; rg++) {
            const float4* ap = (const float4*)(x + (size_t)rowc[rg] * F_IN + kg * 8 + kk * 32);
            float4 alo = ap[0];
            float4 ahi = ap[1];
            afrag[rg][0] = (short)f2bf(alo.x); afrag[rg][1] = (short)f2bf(alo.y);
            afrag[rg][2] = (short)f2bf(alo.z); afrag[rg][3] = (short)f2bf(alo.w);
            afrag[rg][4] = (short)f2bf(ahi.x); afrag[rg][5] = (short)f2bf(ahi.y);
            afrag[rg][6] = (short)f2bf(ahi.z); afrag[rg][7] = (short)f2bf(ahi.w);
        }
        const u16* bcol = W1T + kg * 8 + kk * 32;
#pragma unroll
        for (int ct = 0; ct < 8; ct++) {
            bf16x8 bfrag = *(const bf16x8*)(bcol + (size_t)(ct * 16 + lr) * F_IN);
#pragma unroll
            for (int rg = 0; rg < 4; rg++)
                acc[rg][ct] = __builtin_amdgcn_mfma_f32_16x16x32_bf16(afrag[rg], bfrag, acc[rg][ct], 0, 0, 0);
        }
    }

    // store: T1[r0 + rg*16 + kg*4 + i][ct*16 + lr]
#pragma unroll
    for (int rg = 0; rg < 4; rg++) {
        int rbase = r0 + rg * 16 + kg * 4;
#pragma unroll
        for (int ct = 0; ct < 8; ct++) {
#pragma unroll
            for (int i = 0; i < 4; i++) {
                int row = rbase + i;
                if (row < n)
                    T1[(size_t)row * HDIM + ct * 16 + lr] = f2bf(acc[rg][ct][i]);
            }
        }
    }
}

// ---------------- K4: H = relu(SpMM(T1) + b1)  (bf16 in/out) ----------------
// 4 waves/block, 1 row/wave. Wave = 4x 16-lane subgroups, each owns one edge.
// Lane gathers 16B (8 bf16 features). x2 unroll -> 8 outstanding gathers/wave.
__global__ __launch_bounds__(256) void k_spmm1(const u16* __restrict__ T1,
                                               const float* __restrict__ wn,
                                               const int* __restrict__ rowptr,
                                               const int* __restrict__ col,
                                               const float* __restrict__ b1,
                                               u16* __restrict__ H, int n) {
    int wave = threadIdx.x >> 6;
    int lane = threadIdx.x & 63;
    int r = blockIdx.x * 4 + wave;
    if (r >= n) return;
    int es = lane >> 4;          // subgroup 0..3 (edge slot)
    int fl = lane & 15;          // feature group: features fl*8 .. fl*8+7

    int s = rowptr[r], e = rowptr[r + 1];
    float a[8];
#pragma unroll
    for (int j = 0; j < 8; j++) a[j] = 0.f;

    int i = s + es;
    for (; i + 4 < e; i += 8) {
        float w0 = wn[i];
        int c0 = col[i];
        float w1 = wn[i + 4];
        int c1 = col[i + 4];
        uint4 p0 = *(const uint4*)(T1 + (size_t)c0 * HDIM + fl * 8);
        uint4 p1 = *(const uint4*)(T1 + (size_t)c1 * HDIM + fl * 8);
        a[0] += w0 * bf2f(p0.x & 0xFFFFu); a[1] += w0 * bf2f(p0.x >> 16);
        a[2] += w0 * bf2f(p0.y & 0xFFFFu); a[3] += w0 * bf2f(p0.y >> 16);
        a[4] += w0 * bf2f(p0.z & 0xFFFFu); a[5] += w0 * bf2f(p0.z >> 16);
        a[6] += w0 * bf2f(p0.w & 0xFFFFu); a[7] += w0 * bf2f(p0.w >> 16);
        a[0] += w1 * bf2f(p1.x & 0xFFFFu); a[1] += w1 * bf2f(p1.x >> 16);
        a[2] += w1 * bf2f(p1.y & 0xFFFFu); a[3] += w1 * bf2f(p1.y >> 16);
        a[4] += w1 * bf2f(p1.z & 0xFFFFu); a[5] += w1 * bf2f(p1.z >> 16);
        a[6] += w1 * bf2f(p1.w & 0xFFFFu); a[7] += w1 * bf2f(p1.w >> 16);
    }
    if (i < e) {
        float w0 = wn[i];
        int c0 = col[i];
        uint4 p0 = *(const uint4*)(T1 + (size_t)c0 * HDIM + fl * 8);
        a[0] += w0 * bf2f(p0.x & 0xFFFFu); a[1] += w0 * bf2f(p0.x >> 16);
        a[2] += w0 * bf2f(p0.y & 0xFFFFu); a[3] += w0 * bf2f(p0.y >> 16);
        a[4] += w0 * bf2f(p0.z & 0xFFFFu); a[5] += w0 * bf2f(p0.z >> 16);
        a[6] += w0 * bf2f(p0.w & 0xFFFFu); a[7] += w0 * bf2f(p0.w >> 16);
    }

    // reduce across the 4 edge subgroups
#pragma unroll
    for (int j = 0; j < 8; j++) {
        a[j] += __shfl_xor(a[j], 16);
        a[j] += __shfl_xor(a[j], 32);
    }

    if (es == 0) {
        const float4* bb = (const float4*)(b1 + fl * 8);
        float4 blo = bb[0], bhi = bb[1];
        float v0 = a[0] + blo.x, v1 = a[1] + blo.y;
        float v2 = a[2] + blo.z, v3 = a[3] + blo.w;
        float v4 = a[4] + bhi.x, v5 = a[5] + bhi.y;
        float v6 = a[6] + bhi.z, v7 = a[7] + bhi.w;
        v0 = v0 > 0.f ? v0 : 0.f; v1 = v1 > 0.f ? v1 : 0.f;
        v2 = v2 > 0.f ? v2 : 0.f; v3 = v3 > 0.f ? v3 : 0.f;
        v4 = v4 > 0.f ? v4 : 0.f; v5 = v5 > 0.f ? v5 : 0.f;
        v6 = v6 > 0.f ? v6 : 0.f; v7 = v7 > 0.f ? v7 : 0.f;
        uint4 o;
        o.x = pack2(v0, v1); o.y = pack2(v2, v3);
        o.z = pack2(v4, v5); o.w = pack2(v6, v7);
        *(uint4*)(H + (size_t)r * HDIM + fl * 8) = o;
    }
}

// ---------------- K5: U = H @ W2  (bf16 in, f32 out) ----------------
__global__ __launch_bounds__(256) void k_gemm2(const u16* __restrict__ H,
                                               const float* __restrict__ W2,
                                               float* __restrict__ U, int n) {
    int rl = threadIdx.x >> 4;
    int f = threadIdx.x & 15;
    int row = blockIdx.x * 16 + rl;
    if (row >= n) return;
    const u32* hr = (const u32*)(H + (size_t)row * HDIM);
    float acc = 0.f;
    for (int k2 = 0; k2 < HDIM / 2; k2++) {
        u32 pr = hr[k2];
        float h0 = bf2f(pr & 0xFFFFu);
        float h1 = bf2f(pr >> 16);
        acc += h0 * W2[(size_t)(k2 * 2) * CDIM + f];
        acc += h1 * W2[(size_t)(k2 * 2 + 1) * CDIM + f];
    }
    U[(size_t)row * CDIM + f] = acc;
}

// ---------------- K6: out = log_softmax(SpMM(U) + b2) ----------------
// 4 waves/block, 1 row/wave: 4 parallel edges x 16 features, x2 unroll
__global__ __launch_bounds__(256) void k_out(const float* __restrict__ U,
                                             const float* __restrict__ wn,
                                             const int* __restrict__ rowptr,
                                             const int* __restrict__ col,
                                             const float* __restrict__ b2,
                                             float* __restrict__ out, int n) {
    int wave = threadIdx.x >> 6;
    int lane = threadIdx.x & 63;
    int r = blockIdx.x * 4 + wave;
    if (r >= n) return;
    int es = lane >> 4;   // 0..3
    int f = lane & 15;
    int s = rowptr[r], e = rowptr[r + 1];
    float acc = 0.f;
    int i = s + es;
    for (; i + 4 < e; i += 8) {
        float w0 = wn[i];
        int c0 = col[i];
        float w1 = wn[i + 4];
        int c1 = col[i + 4];
        acc += w0 * U[(size_t)c0 * CDIM + f];
        acc += w1 * U[(size_t)c1 * CDIM + f];
    }
    if (i < e) {
        acc += wn[i] * U[(size_t)col[i] * CDIM + f];
    }
    // reduce across the 4 edge sub-groups
    acc += __shfl_xor(acc, 16);
    acc += __shfl_xor(acc, 32);
    float v = acc + b2[f];
    // log-softmax over 16 lanes
    float m = v;
    for (int d = 1; d < 16; d <<= 1) m = fmaxf(m, __shfl_xor(m, d));
    float ex = __expf(v - m);
    float ss = ex;
    for (int d = 1; d < 16; d <<= 1) ss += __shfl_xor(ss, d);
    float res = v - m - __logf(ss);
    if (es == 0) out[(size_t)r * CDIM + f] = res;
}

extern "C" void kernel_launch(void* const* d_in, const int* in_sizes, int n_in,
                              void* d_out, int out_size, void* d_ws, size_t ws_size,
                              hipStream_t stream) {
    const float* x      = (const float*)d_in[0];
    const float* ew     = (const float*)d_in[1];
    const float* W1     = (const float*)d_in[2];
    const float* b1     = (const float*)d_in[3];
    const float* W2     = (const float*)d_in[4];
    const float* b2     = (const float*)d_in[5];
    const int*   rowptr = (const int*)d_in[6];
    const int*   colind = (const int*)d_in[7];

    int n = in_sizes[6] - 1;   // rowptr has n+1 entries
    int E = in_sizes[7];

    auto align256 = [](size_t v) { return (v + 255) & ~(size_t)255; };
    char* p = (char*)d_ws;
    float* dinv = (float*)p; p += align256((size_t)n * 4);
    float* wn   = (float*)p; p += align256((size_t)E * 4);
    u16*   T1   = (u16*)p;   p += align256((size_t)n * HDIM * 2);
    u16*   H    = (u16*)p;   p += align256((size_t)n * HDIM * 2);
    float* U    = (float*)p; p += align256((size_t)n * CDIM * 4);
    u16*   W1T  = (u16*)p;   p += align256((size_t)HDIM * F_IN * 2);
    float* out  = (float*)d_out;

    k_dinv<<<(n + 255) / 256, 256, 0, stream>>>(ew, rowptr, dinv, n);
    k_w<<<(n + 255) / 256, 256, 0, stream>>>(ew, rowptr, colind, dinv, wn, n);
    k_prepw1<<<(HDIM * F_IN + 255) / 256, 256, 0, stream>>>(W1, W1T);

    k_gemm1<<<(n + 255) / 256, 256, 0, stream>>>(x, W1T, T1, n);

    k_spmm1<<<(n + 3) / 4, 256, 0, stream>>>(T1, wn, rowptr, colind, b1, H, n);
    k_gemm2<<<(n + 15) / 16, 256, 0, stream>>>(H, W2, U, n);
    k_out<<<(n + 3) / 4, 256, 0, stream>>>(U, wn, rowptr, colind, b2, out, n);
}

// Round 5
// 201.810 us; speedup vs baseline: 4.7678x; 1.0769x over previous
//
#include <hip/hip_runtime.h>
#include <hip/hip_bf16.h>

#define F_IN 256
#define HDIM 128
#define CDIM 16

typedef unsigned short u16;
typedef unsigned int u32;

typedef __attribute__((ext_vector_type(8))) short bf16x8;
typedef __attribute__((ext_vector_type(4))) float f32x4;

__device__ __forceinline__ float bf2f(u32 v) {
    u32 u = v << 16;
    float f;
    __builtin_memcpy(&f, &u, 4);
    return f;
}
__device__ __forceinline__ u16 f2bf(float f) {
    u32 u;
    __builtin_memcpy(&u, &f, 4);
    u32 r = (u + 0x7FFFu + ((u >> 16) & 1u)) >> 16;
    return (u16)r;
}
__device__ __forceinline__ u32 pack2(float lo, float hi) {
    return ((u32)f2bf(hi) << 16) | (u32)f2bf(lo);
}

// ---------------- K1: dinv[r] = rsqrt(sum_e ew[e]) ----------------
__global__ void k_dinv(const float* __restrict__ ew, const int* __restrict__ rowptr,
                       float* __restrict__ dinv, int n) {
    int r = blockIdx.x * blockDim.x + threadIdx.x;
    if (r >= n) return;
    int s = rowptr[r], e = rowptr[r + 1];
    float acc = 0.f;
    for (int i = s; i < e; i++) acc += ew[i];
    dinv[r] = (acc > 0.f) ? rsqrtf(acc) : 0.f;
}

// ---------------- K2: w[e] = dinv[row]*ew[e]*dinv[col[e]] ----------------
__global__ void k_w(const float* __restrict__ ew, const int* __restrict__ rowptr,
                    const int* __restrict__ col, const float* __restrict__ dinv,
                    float* __restrict__ wn, int n) {
    int r = blockIdx.x * blockDim.x + threadIdx.x;
    if (r >= n) return;
    float dr = dinv[r];
    int s = rowptr[r], e = rowptr[r + 1];
    for (int i = s; i < e; i++) wn[i] = dr * ew[i] * dinv[col[i]];
}

// ---------------- K-prep: W1T[f][k] = bf16(W1[k][f])  (128x256 bf16) ----------------
__global__ void k_prepw1(const float* __restrict__ W1, u16* __restrict__ W1T) {
    int idx = blockIdx.x * blockDim.x + threadIdx.x;   // 0..32767
    if (idx >= HDIM * F_IN) return;
    int f = idx >> 8;         // 0..127
    int k = idx & 255;        // 0..255
    W1T[idx] = f2bf(W1[(size_t)k * HDIM + f]);
}

// ---------------- K3: T1 = x @ W1 via bf16 MFMA, W1T staged in LDS ----------
// Block = 4 waves x 32 rows = 128 rows. Full W1T (64 KB bf16) in LDS,
// XOR-swizzled (byte ^= (row&7)<<4) to kill the stride-512B bank conflict.
// A-frag: lane reads x[row][kk*32 + kg*8 .. +8] (2x float4 -> bf16)
// B-frag: ds_read_b128 from swizzled LDS.
// D: col = lane&15, row = (lane>>4)*4 + reg   [m89-verified]
__global__ __launch_bounds__(256) void k_gemm1(const float* __restrict__ x,
                                               const u16* __restrict__ W1T,
                                               u16* __restrict__ T1, int n) {
    __shared__ u16 Bs[HDIM * F_IN];   // 64 KB

    int tid = threadIdx.x;
    // stage W1T -> LDS, swizzled: value at linear byte o lands at o ^ ((row&7)<<4)
#pragma unroll
    for (int it = 0; it < 16; it++) {
        int o16 = it * 256 + tid;            // 16B-granule index 0..4095
        u32 o = (u32)o16 * 16;               // linear byte offset
        u32 swz = o ^ (((o >> 9) & 7u) << 4);
        uint4 v = ((const uint4*)W1T)[o16];
        *(uint4*)((char*)Bs + swz) = v;
    }
    __syncthreads();

    int wave = tid >> 6;
    int lane = tid & 63;
    int lr = lane & 15;
    int kg = lane >> 4;
    int r0 = blockIdx.x * 128 + wave * 32;
    if (r0 >= n) return;

    f32x4 acc[2][8];
#pragma unroll
    for (int rg = 0; rg < 2; rg++)
#pragma unroll
        for (int ct = 0; ct < 8; ct++) acc[rg][ct] = (f32x4){0.f, 0.f, 0.f, 0.f};

    int rowc[2];
#pragma unroll
    for (int rg = 0; rg < 2; rg++) {
        int row = r0 + rg * 16 + lr;
        rowc[rg] = row < n ? row : (n - 1);
    }

#pragma unroll
    for (int kk = 0; kk < F_IN / 32; kk++) {
        bf16x8 afrag[2];
#pragma unroll
        for (int rg = 0; rg < 2; rg++) {
            const float4* ap = (const float4*)(x + (size_t)rowc[rg] * F_IN + kg * 8 + kk * 32);
            float4 alo = ap[0];
            float4 ahi = ap[1];
            afrag[rg][0] = (short)f2bf(alo.x); afrag[rg][1] = (short)f2bf(alo.y);
            afrag[rg][2] = (short)f2bf(alo.z); afrag[rg][3] = (short)f2bf(alo.w);
            afrag[rg][4] = (short)f2bf(ahi.x); afrag[rg][5] = (short)f2bf(ahi.y);
            afrag[rg][6] = (short)f2bf(ahi.z); afrag[rg][7] = (short)f2bf(ahi.w);
        }
#pragma unroll
        for (int ct = 0; ct < 8; ct++) {
            u32 a = (u32)(ct * 16 + lr) * (F_IN * 2) + (u32)kg * 16 + (u32)kk * 64;
            u32 aswz = a ^ (((a >> 9) & 7u) << 4);
            bf16x8 bfrag = *(const bf16x8*)((const char*)Bs + aswz);
#pragma unroll
            for (int rg = 0; rg < 2; rg++)
                acc[rg][ct] = __builtin_amdgcn_mfma_f32_16x16x32_bf16(afrag[rg], bfrag, acc[rg][ct], 0, 0, 0);
        }
    }

    // store: T1[r0 + rg*16 + kg*4 + i][ct*16 + lr]
#pragma unroll
    for (int rg = 0; rg < 2; rg++) {
        int rbase = r0 + rg * 16 + kg * 4;
#pragma unroll
        for (int ct = 0; ct < 8; ct++) {
#pragma unroll
            for (int i = 0; i < 4; i++) {
                int row = rbase + i;
                if (row < n)
                    T1[(size_t)row * HDIM + ct * 16 + lr] = f2bf(acc[rg][ct][i]);
            }
        }
    }
}

// ---------------- K4: H = relu(SpMM(T1) + b1)  (bf16 in/out) ----------------
// 4 waves/block, 1 row/wave. Wave = 4x 16-lane subgroups, each owns one edge.
// Lane gathers 16B (8 bf16 features). x2 unroll -> 8 outstanding gathers/wave.
__global__ __launch_bounds__(256) void k_spmm1(const u16* __restrict__ T1,
                                               const float* __restrict__ wn,
                                               const int* __restrict__ rowptr,
                                               const int* __restrict__ col,
                                               const float* __restrict__ b1,
                                               u16* __restrict__ H, int n) {
    int wave = threadIdx.x >> 6;
    int lane = threadIdx.x & 63;
    int r = blockIdx.x * 4 + wave;
    if (r >= n) return;
    int es = lane >> 4;          // subgroup 0..3 (edge slot)
    int fl = lane & 15;          // feature group: features fl*8 .. fl*8+7

    int s = rowptr[r], e = rowptr[r + 1];
    float a[8];
#pragma unroll
    for (int j = 0; j < 8; j++) a[j] = 0.f;

    int i = s + es;
    for (; i + 4 < e; i += 8) {
        float w0 = wn[i];
        int c0 = col[i];
        float w1 = wn[i + 4];
        int c1 = col[i + 4];
        uint4 p0 = *(const uint4*)(T1 + (size_t)c0 * HDIM + fl * 8);
        uint4 p1 = *(const uint4*)(T1 + (size_t)c1 * HDIM + fl * 8);
        a[0] += w0 * bf2f(p0.x & 0xFFFFu); a[1] += w0 * bf2f(p0.x >> 16);
        a[2] += w0 * bf2f(p0.y & 0xFFFFu); a[3] += w0 * bf2f(p0.y >> 16);
        a[4] += w0 * bf2f(p0.z & 0xFFFFu); a[5] += w0 * bf2f(p0.z >> 16);
        a[6] += w0 * bf2f(p0.w & 0xFFFFu); a[7] += w0 * bf2f(p0.w >> 16);
        a[0] += w1 * bf2f(p1.x & 0xFFFFu); a[1] += w1 * bf2f(p1.x >> 16);
        a[2] += w1 * bf2f(p1.y & 0xFFFFu); a[3] += w1 * bf2f(p1.y >> 16);
        a[4] += w1 * bf2f(p1.z & 0xFFFFu); a[5] += w1 * bf2f(p1.z >> 16);
        a[6] += w1 * bf2f(p1.w & 0xFFFFu); a[7] += w1 * bf2f(p1.w >> 16);
    }
    if (i < e) {
        float w0 = wn[i];
        int c0 = col[i];
        uint4 p0 = *(const uint4*)(T1 + (size_t)c0 * HDIM + fl * 8);
        a[0] += w0 * bf2f(p0.x & 0xFFFFu); a[1] += w0 * bf2f(p0.x >> 16);
        a[2] += w0 * bf2f(p0.y & 0xFFFFu); a[3] += w0 * bf2f(p0.y >> 16);
        a[4] += w0 * bf2f(p0.z & 0xFFFFu); a[5] += w0 * bf2f(p0.z >> 16);
        a[6] += w0 * bf2f(p0.w & 0xFFFFu); a[7] += w0 * bf2f(p0.w >> 16);
    }

    // reduce across the 4 edge subgroups
#pragma unroll
    for (int j = 0; j < 8; j++) {
        a[j] += __shfl_xor(a[j], 16);
        a[j] += __shfl_xor(a[j], 32);
    }

    if (es == 0) {
        const float4* bb = (const float4*)(b1 + fl * 8);
        float4 blo = bb[0], bhi = bb[1];
        float v0 = a[0] + blo.x, v1 = a[1] + blo.y;
        float v2 = a[2] + blo.z, v3 = a[3] + blo.w;
        float v4 = a[4] + bhi.x, v5 = a[5] + bhi.y;
        float v6 = a[6] + bhi.z, v7 = a[7] + bhi.w;
        v0 = v0 > 0.f ? v0 : 0.f; v1 = v1 > 0.f ? v1 : 0.f;
        v2 = v2 > 0.f ? v2 : 0.f; v3 = v3 > 0.f ? v3 : 0.f;
        v4 = v4 > 0.f ? v4 : 0.f; v5 = v5 > 0.f ? v5 : 0.f;
        v6 = v6 > 0.f ? v6 : 0.f; v7 = v7 > 0.f ? v7 : 0.f;
        uint4 o;
        o.x = pack2(v0, v1); o.y = pack2(v2, v3);
        o.z = pack2(v4, v5); o.w = pack2(v6, v7);
        *(uint4*)(H + (size_t)r * HDIM + fl * 8) = o;
    }
}

// ---------------- K5: U = H @ W2  (bf16 in, f32 out) ----------------
__global__ __launch_bounds__(256) void k_gemm2(const u16* __restrict__ H,
                                               const float* __restrict__ W2,
                                               float* __restrict__ U, int n) {
    int rl = threadIdx.x >> 4;
    int f = threadIdx.x & 15;
    int row = blockIdx.x * 16 + rl;
    if (row >= n) return;
    const u32* hr = (const u32*)(H + (size_t)row * HDIM);
    float acc = 0.f;
    for (int k2 = 0; k2 < HDIM / 2; k2++) {
        u32 pr = hr[k2];
        float h0 = bf2f(pr & 0xFFFFu);
        float h1 = bf2f(pr >> 16);
        acc += h0 * W2[(size_t)(k2 * 2) * CDIM + f];
        acc += h1 * W2[(size_t)(k2 * 2 + 1) * CDIM + f];
    }
    U[(size_t)row * CDIM + f] = acc;
}

// ---------------- K6: out = log_softmax(SpMM(U) + b2) ----------------
// 4 waves/block, 1 row/wave: 4 parallel edges x 16 features, x2 unroll
__global__ __launch_bounds__(256) void k_out(const float* __restrict__ U,
                                             const float* __restrict__ wn,
                                             const int* __restrict__ rowptr,
                                             const int* __restrict__ col,
                                             const float* __restrict__ b2,
                                             float* __restrict__ out, int n) {
    int wave = threadIdx.x >> 6;
    int lane = threadIdx.x & 63;
    int r = blockIdx.x * 4 + wave;
    if (r >= n) return;
    int es = lane >> 4;   // 0..3
    int f = lane & 15;
    int s = rowptr[r], e = rowptr[r + 1];
    float acc = 0.f;
    int i = s + es;
    for (; i + 4 < e; i += 8) {
        float w0 = wn[i];
        int c0 = col[i];
        float w1 = wn[i + 4];
        int c1 = col[i + 4];
        acc += w0 * U[(size_t)c0 * CDIM + f];
        acc += w1 * U[(size_t)c1 * CDIM + f];
    }
    if (i < e) {
        acc += wn[i] * U[(size_t)col[i] * CDIM + f];
    }
    // reduce across the 4 edge sub-groups
    acc += __shfl_xor(acc, 16);
    acc += __shfl_xor(acc, 32);
    float v = acc + b2[f];
    // log-softmax over 16 lanes
    float m = v;
    for (int d = 1; d < 16; d <<= 1) m = fmaxf(m, __shfl_xor(m, d));
    float ex = __expf(v - m);
    float ss = ex;
    for (int d = 1; d < 16; d <<= 1) ss += __shfl_xor(ss, d);
    float res = v - m - __logf(ss);
    if (es == 0) out[(size_t)r * CDIM + f] = res;
}

extern "C" void kernel_launch(void* const* d_in, const int* in_sizes, int n_in,
                              void* d_out, int out_size, void* d_ws, size_t ws_size,
                              hipStream_t stream) {
    const float* x      = (const float*)d_in[0];
    const float* ew     = (const float*)d_in[1];
    const float* W1     = (const float*)d_in[2];
    const float* b1     = (const float*)d_in[3];
    const float* W2     = (const float*)d_in[4];
    const float* b2     = (const float*)d_in[5];
    const int*   rowptr = (const int*)d_in[6];
    const int*   colind = (const int*)d_in[7];

    int n = in_sizes[6] - 1;   // rowptr has n+1 entries
    int E = in_sizes[7];

    auto align256 = [](size_t v) { return (v + 255) & ~(size_t)255; };
    char* p = (char*)d_ws;
    float* dinv = (float*)p; p += align256((size_t)n * 4);
    float* wn   = (float*)p; p += align256((size_t)E * 4);
    u16*   T1   = (u16*)p;   p += align256((size_t)n * HDIM * 2);
    u16*   H    = (u16*)p;   p += align256((size_t)n * HDIM * 2);
    float* U    = (float*)p; p += align256((size_t)n * CDIM * 4);
    u16*   W1T  = (u16*)p;   p += align256((size_t)HDIM * F_IN * 2);
    float* out  = (float*)d_out;

    k_dinv<<<(n + 255) / 256, 256, 0, stream>>>(ew, rowptr, dinv, n);
    k_w<<<(n + 255) / 256, 256, 0, stream>>>(ew, rowptr, colind, dinv, wn, n);
    k_prepw1<<<(HDIM * F_IN + 255) / 256, 256, 0, stream>>>(W1, W1T);

    k_gemm1<<<(n + 127) / 128, 256, 0, stream>>>(x, W1T, T1, n);

    k_spmm1<<<(n + 3) / 4, 256, 0, stream>>>(T1, wn, rowptr, colind, b1, H, n);
    k_gemm2<<<(n + 15) / 16, 256, 0, stream>>>(H, W2, U, n);
    k_out<<<(n + 3) / 4, 256, 0, stream>>>(U, wn, rowptr, colind, b2, out, n);
}

// Round 6
// 198.749 us; speedup vs baseline: 4.8413x; 1.0154x over previous
//
#include <hip/hip_runtime.h>
#include <hip/hip_bf16.h>

#define F_IN 256
#define HDIM 128
#define CDIM 16

typedef unsigned short u16;
typedef unsigned int u32;

typedef __attribute__((ext_vector_type(8))) short bf16x8;
typedef __attribute__((ext_vector_type(4))) float f32x4;

__device__ __forceinline__ float bf2f(u32 v) {
    u32 u = v << 16;
    float f;
    __builtin_memcpy(&f, &u, 4);
    return f;
}
__device__ __forceinline__ u16 f2bf(float f) {
    u32 u;
    __builtin_memcpy(&u, &f, 4);
    u32 r = (u + 0x7FFFu + ((u >> 16) & 1u)) >> 16;
    return (u16)r;
}
__device__ __forceinline__ u32 pack2(float lo, float hi) {
    return ((u32)f2bf(hi) << 16) | (u32)f2bf(lo);
}

// ---------------- K1: dinv[r] = rsqrt(sum_e ew[e]) ----------------
__global__ void k_dinv(const float* __restrict__ ew, const int* __restrict__ rowptr,
                       float* __restrict__ dinv, int n) {
    int r = blockIdx.x * blockDim.x + threadIdx.x;
    if (r >= n) return;
    int s = rowptr[r], e = rowptr[r + 1];
    float acc = 0.f;
    for (int i = s; i < e; i++) acc += ew[i];
    dinv[r] = (acc > 0.f) ? rsqrtf(acc) : 0.f;
}

// ---------------- K2: w[e] = dinv[row]*ew[e]*dinv[col[e]] ----------------
__global__ void k_w(const float* __restrict__ ew, const int* __restrict__ rowptr,
                    const int* __restrict__ col, const float* __restrict__ dinv,
                    float* __restrict__ wn, int n) {
    int r = blockIdx.x * blockDim.x + threadIdx.x;
    if (r >= n) return;
    float dr = dinv[r];
    int s = rowptr[r], e = rowptr[r + 1];
    for (int i = s; i < e; i++) wn[i] = dr * ew[i] * dinv[col[i]];
}

// ---------------- K-prep: W1T[f][k] = bf16(W1[k][f])  (128x256 bf16) ----------------
__global__ void k_prepw1(const float* __restrict__ W1, u16* __restrict__ W1T) {
    int idx = blockIdx.x * blockDim.x + threadIdx.x;   // 0..32767
    if (idx >= HDIM * F_IN) return;
    int f = idx >> 8;         // 0..127
    int k = idx & 255;        // 0..255
    W1T[idx] = f2bf(W1[(size_t)k * HDIM + f]);
}

// ---------------- K3: T1 = x @ W1 via bf16 MFMA, W1T staged in LDS ----------
// Block = 8 waves x 32 rows = 256 rows. Full W1T (64 KB bf16) in LDS,
// XOR-swizzled (byte ^= (row&7)<<4). 2 blocks/CU -> 16 waves/CU = 4/SIMD.
// A-frag: lane reads x[row][kk*32 + kg*8 .. +8] (2x float4 -> bf16)
// B-frag: ds_read_b128 from swizzled LDS.
// D: col = lane&15, row = (lane>>4)*4 + reg   [m89-verified]
__global__ __launch_bounds__(512, 4) void k_gemm1(const float* __restrict__ x,
                                                  const u16* __restrict__ W1T,
                                                  u16* __restrict__ T1, int n) {
    __shared__ u16 Bs[HDIM * F_IN];   // 64 KB

    int tid = threadIdx.x;
    // stage W1T -> LDS, swizzled: value at linear byte o lands at o ^ ((row&7)<<4)
#pragma unroll
    for (int it = 0; it < 8; it++) {
        int o16 = it * 512 + tid;            // 16B-granule index 0..4095
        u32 o = (u32)o16 * 16;               // linear byte offset
        u32 swz = o ^ (((o >> 9) & 7u) << 4);
        uint4 v = ((const uint4*)W1T)[o16];
        *(uint4*)((char*)Bs + swz) = v;
    }
    __syncthreads();

    int wave = tid >> 6;
    int lane = tid & 63;
    int lr = lane & 15;
    int kg = lane >> 4;
    int r0 = blockIdx.x * 256 + wave * 32;
    if (r0 >= n) return;

    f32x4 acc[2][8];
#pragma unroll
    for (int rg = 0; rg < 2; rg++)
#pragma unroll
        for (int ct = 0; ct < 8; ct++) acc[rg][ct] = (f32x4){0.f, 0.f, 0.f, 0.f};

    int rowc[2];
#pragma unroll
    for (int rg = 0; rg < 2; rg++) {
        int row = r0 + rg * 16 + lr;
        rowc[rg] = row < n ? row : (n - 1);
    }

#pragma unroll
    for (int kk = 0; kk < F_IN / 32; kk++) {
        bf16x8 afrag[2];
#pragma unroll
        for (int rg = 0; rg < 2; rg++) {
            const float4* ap = (const float4*)(x + (size_t)rowc[rg] * F_IN + kg * 8 + kk * 32);
            float4 alo = ap[0];
            float4 ahi = ap[1];
            afrag[rg][0] = (short)f2bf(alo.x); afrag[rg][1] = (short)f2bf(alo.y);
            afrag[rg][2] = (short)f2bf(alo.z); afrag[rg][3] = (short)f2bf(alo.w);
            afrag[rg][4] = (short)f2bf(ahi.x); afrag[rg][5] = (short)f2bf(ahi.y);
            afrag[rg][6] = (short)f2bf(ahi.z); afrag[rg][7] = (short)f2bf(ahi.w);
        }
#pragma unroll
        for (int ct = 0; ct < 8; ct++) {
            u32 a = (u32)(ct * 16 + lr) * (F_IN * 2) + (u32)kg * 16 + (u32)kk * 64;
            u32 aswz = a ^ (((a >> 9) & 7u) << 4);
            bf16x8 bfrag = *(const bf16x8*)((const char*)Bs + aswz);
#pragma unroll
            for (int rg = 0; rg < 2; rg++)
                acc[rg][ct] = __builtin_amdgcn_mfma_f32_16x16x32_bf16(afrag[rg], bfrag, acc[rg][ct], 0, 0, 0);
        }
    }

    // store: T1[r0 + rg*16 + kg*4 + i][ct*16 + lr]
#pragma unroll
    for (int rg = 0; rg < 2; rg++) {
        int rbase = r0 + rg * 16 + kg * 4;
#pragma unroll
        for (int ct = 0; ct < 8; ct++) {
#pragma unroll
            for (int i = 0; i < 4; i++) {
                int row = rbase + i;
                if (row < n)
                    T1[(size_t)row * HDIM + ct * 16 + lr] = f2bf(acc[rg][ct][i]);
            }
        }
    }
}

// ---------------- K4: H = relu(SpMM(T1) + b1)  (bf16 in/out) ----------------
// 4 waves/block, 1 row/wave. Wave = 4x 16-lane subgroups, each owns one edge.
// Lane gathers 16B (8 bf16 features). x2 unroll -> 8 outstanding gathers/wave.
__global__ __launch_bounds__(256) void k_spmm1(const u16* __restrict__ T1,
                                               const float* __restrict__ wn,
                                               const int* __restrict__ rowptr,
                                               const int* __restrict__ col,
                                               const float* __restrict__ b1,
                                               u16* __restrict__ H, int n) {
    int wave = threadIdx.x >> 6;
    int lane = threadIdx.x & 63;
    int r = blockIdx.x * 4 + wave;
    if (r >= n) return;
    int es = lane >> 4;          // subgroup 0..3 (edge slot)
    int fl = lane & 15;          // feature group: features fl*8 .. fl*8+7

    int s = rowptr[r], e = rowptr[r + 1];
    float a[8];
#pragma unroll
    for (int j = 0; j < 8; j++) a[j] = 0.f;

    int i = s + es;
    for (; i + 4 < e; i += 8) {
        float w0 = wn[i];
        int c0 = col[i];
        float w1 = wn[i + 4];
        int c1 = col[i + 4];
        uint4 p0 = *(const uint4*)(T1 + (size_t)c0 * HDIM + fl * 8);
        uint4 p1 = *(const uint4*)(T1 + (size_t)c1 * HDIM + fl * 8);
        a[0] += w0 * bf2f(p0.x & 0xFFFFu); a[1] += w0 * bf2f(p0.x >> 16);
        a[2] += w0 * bf2f(p0.y & 0xFFFFu); a[3] += w0 * bf2f(p0.y >> 16);
        a[4] += w0 * bf2f(p0.z & 0xFFFFu); a[5] += w0 * bf2f(p0.z >> 16);
        a[6] += w0 * bf2f(p0.w & 0xFFFFu); a[7] += w0 * bf2f(p0.w >> 16);
        a[0] += w1 * bf2f(p1.x & 0xFFFFu); a[1] += w1 * bf2f(p1.x >> 16);
        a[2] += w1 * bf2f(p1.y & 0xFFFFu); a[3] += w1 * bf2f(p1.y >> 16);
        a[4] += w1 * bf2f(p1.z & 0xFFFFu); a[5] += w1 * bf2f(p1.z >> 16);
        a[6] += w1 * bf2f(p1.w & 0xFFFFu); a[7] += w1 * bf2f(p1.w >> 16);
    }
    if (i < e) {
        float w0 = wn[i];
        int c0 = col[i];
        uint4 p0 = *(const uint4*)(T1 + (size_t)c0 * HDIM + fl * 8);
        a[0] += w0 * bf2f(p0.x & 0xFFFFu); a[1] += w0 * bf2f(p0.x >> 16);
        a[2] += w0 * bf2f(p0.y & 0xFFFFu); a[3] += w0 * bf2f(p0.y >> 16);
        a[4] += w0 * bf2f(p0.z & 0xFFFFu); a[5] += w0 * bf2f(p0.z >> 16);
        a[6] += w0 * bf2f(p0.w & 0xFFFFu); a[7] += w0 * bf2f(p0.w >> 16);
    }

    // reduce across the 4 edge subgroups
#pragma unroll
    for (int j = 0; j < 8; j++) {
        a[j] += __shfl_xor(a[j], 16);
        a[j] += __shfl_xor(a[j], 32);
    }

    if (es == 0) {
        const float4* bb = (const float4*)(b1 + fl * 8);
        float4 blo = bb[0], bhi = bb[1];
        float v0 = a[0] + blo.x, v1 = a[1] + blo.y;
        float v2 = a[2] + blo.z, v3 = a[3] + blo.w;
        float v4 = a[4] + bhi.x, v5 = a[5] + bhi.y;
        float v6 = a[6] + bhi.z, v7 = a[7] + bhi.w;
        v0 = v0 > 0.f ? v0 : 0.f; v1 = v1 > 0.f ? v1 : 0.f;
        v2 = v2 > 0.f ? v2 : 0.f; v3 = v3 > 0.f ? v3 : 0.f;
        v4 = v4 > 0.f ? v4 : 0.f; v5 = v5 > 0.f ? v5 : 0.f;
        v6 = v6 > 0.f ? v6 : 0.f; v7 = v7 > 0.f ? v7 : 0.f;
        uint4 o;
        o.x = pack2(v0, v1); o.y = pack2(v2, v3);
        o.z = pack2(v4, v5); o.w = pack2(v6, v7);
        *(uint4*)(H + (size_t)r * HDIM + fl * 8) = o;
    }
}

// ---------------- K5: U = H @ W2  (bf16 in, f32 out) ----------------
__global__ __launch_bounds__(256) void k_gemm2(const u16* __restrict__ H,
                                               const float* __restrict__ W2,
                                               float* __restrict__ U, int n) {
    int rl = threadIdx.x >> 4;
    int f = threadIdx.x & 15;
    int row = blockIdx.x * 16 + rl;
    if (row >= n) return;
    const u32* hr = (const u32*)(H + (size_t)row * HDIM);
    float acc = 0.f;
    for (int k2 = 0; k2 < HDIM / 2; k2++) {
        u32 pr = hr[k2];
        float h0 = bf2f(pr & 0xFFFFu);
        float h1 = bf2f(pr >> 16);
        acc += h0 * W2[(size_t)(k2 * 2) * CDIM + f];
        acc += h1 * W2[(size_t)(k2 * 2 + 1) * CDIM + f];
    }
    U[(size_t)row * CDIM + f] = acc;
}

// ---------------- K6: out = log_softmax(SpMM(U) + b2) ----------------
// 4 waves/block, 1 row/wave: 4 parallel edges x 16 features, x2 unroll
__global__ __launch_bounds__(256) void k_out(const float* __restrict__ U,
                                             const float* __restrict__ wn,
                                             const int* __restrict__ rowptr,
                                             const int* __restrict__ col,
                                             const float* __restrict__ b2,
                                             float* __restrict__ out, int n) {
    int wave = threadIdx.x >> 6;
    int lane = threadIdx.x & 63;
    int r = blockIdx.x * 4 + wave;
    if (r >= n) return;
    int es = lane >> 4;   // 0..3
    int f = lane & 15;
    int s = rowptr[r], e = rowptr[r + 1];
    float acc = 0.f;
    int i = s + es;
    for (; i + 4 < e; i += 8) {
        float w0 = wn[i];
        int c0 = col[i];
        float w1 = wn[i + 4];
        int c1 = col[i + 4];
        acc += w0 * U[(size_t)c0 * CDIM + f];
        acc += w1 * U[(size_t)c1 * CDIM + f];
    }
    if (i < e) {
        acc += wn[i] * U[(size_t)col[i] * CDIM + f];
    }
    // reduce across the 4 edge sub-groups
    acc += __shfl_xor(acc, 16);
    acc += __shfl_xor(acc, 32);
    float v = acc + b2[f];
    // log-softmax over 16 lanes
    float m = v;
    for (int d = 1; d < 16; d <<= 1) m = fmaxf(m, __shfl_xor(m, d));
    float ex = __expf(v - m);
    float ss = ex;
    for (int d = 1; d < 16; d <<= 1) ss += __shfl_xor(ss, d);
    float res = v - m - __logf(ss);
    if (es == 0) out[(size_t)r * CDIM + f] = res;
}

extern "C" void kernel_launch(void* const* d_in, const int* in_sizes, int n_in,
                              void* d_out, int out_size, void* d_ws, size_t ws_size,
                              hipStream_t stream) {
    const float* x      = (const float*)d_in[0];
    const float* ew     = (const float*)d_in[1];
    const float* W1     = (const float*)d_in[2];
    const float* b1     = (const float*)d_in[3];
    const float* W2     = (const float*)d_in[4];
    const float* b2     = (const float*)d_in[5];
    const int*   rowptr = (const int*)d_in[6];
    const int*   colind = (const int*)d_in[7];

    int n = in_sizes[6] - 1;   // rowptr has n+1 entries
    int E = in_sizes[7];

    auto align256 = [](size_t v) { return (v + 255) & ~(size_t)255; };
    char* p = (char*)d_ws;
    float* dinv = (float*)p; p += align256((size_t)n * 4);
    float* wn   = (float*)p; p += align256((size_t)E * 4);
    u16*   T1   = (u16*)p;   p += align256((size_t)n * HDIM * 2);
    u16*   H    = (u16*)p;   p += align256((size_t)n * HDIM * 2);
    float* U    = (float*)p; p += align256((size_t)n * CDIM * 4);
    u16*   W1T  = (u16*)p;   p += align256((size_t)HDIM * F_IN * 2);
    float* out  = (float*)d_out;

    k_dinv<<<(n + 255) / 256, 256, 0, stream>>>(ew, rowptr, dinv, n);
    k_w<<<(n + 255) / 256, 256, 0, stream>>>(ew, rowptr, colind, dinv, wn, n);
    k_prepw1<<<(HDIM * F_IN + 255) / 256, 256, 0, stream>>>(W1, W1T);

    k_gemm1<<<(n + 255) / 256, 512, 0, stream>>>(x, W1T, T1, n);

    k_spmm1<<<(n + 3) / 4, 256, 0, stream>>>(T1, wn, rowptr, colind, b1, H, n);
    k_gemm2<<<(n + 15) / 16, 256, 0, stream>>>(H, W2, U, n);
    k_out<<<(n + 3) / 4, 256, 0, stream>>>(U, wn, rowptr, colind, b2, out, n);
}

// Round 7
// 190.487 us; speedup vs baseline: 5.0513x; 1.0434x over previous
//
#include <hip/hip_runtime.h>
#include <hip/hip_bf16.h>

#define F_IN 256
#define HDIM 128
#define CDIM 16

typedef unsigned short u16;
typedef unsigned int u32;

typedef __attribute__((ext_vector_type(8))) short bf16x8;
typedef __attribute__((ext_vector_type(4))) float f32x4;

__device__ __forceinline__ float bf2f(u32 v) {
    u32 u = v << 16;
    float f;
    __builtin_memcpy(&f, &u, 4);
    return f;
}
__device__ __forceinline__ u16 f2bf(float f) {
    u32 u;
    __builtin_memcpy(&u, &f, 4);
    u32 r = (u + 0x7FFFu + ((u >> 16) & 1u)) >> 16;
    return (u16)r;
}
// v_cvt_pk_bf16_f32: D[15:0]=bf16(lo), D[31:16]=bf16(hi), RNE
__device__ __forceinline__ u32 cvtpk(float lo, float hi) {
    u32 r;
    asm("v_cvt_pk_bf16_f32 %0, %1, %2" : "=v"(r) : "v"(lo), "v"(hi));
    return r;
}

// ---------------- K1: dinv[r] = rsqrt(sum_e ew[e]) ----------------
__global__ void k_dinv(const float* __restrict__ ew, const int* __restrict__ rowptr,
                       float* __restrict__ dinv, int n) {
    int r = blockIdx.x * blockDim.x + threadIdx.x;
    if (r >= n) return;
    int s = rowptr[r], e = rowptr[r + 1];
    float acc = 0.f;
    for (int i = s; i < e; i++) acc += ew[i];
    dinv[r] = (acc > 0.f) ? rsqrtf(acc) : 0.f;
}

// ---------------- K2: w[e] = dinv[row]*ew[e]*dinv[col[e]] ----------------
__global__ void k_w(const float* __restrict__ ew, const int* __restrict__ rowptr,
                    const int* __restrict__ col, const float* __restrict__ dinv,
                    float* __restrict__ wn, int n) {
    int r = blockIdx.x * blockDim.x + threadIdx.x;
    if (r >= n) return;
    float dr = dinv[r];
    int s = rowptr[r], e = rowptr[r + 1];
    for (int i = s; i < e; i++) wn[i] = dr * ew[i] * dinv[col[i]];
}

// ---------------- K-prep: W1T[f][k] = bf16(W1[k][f])  (128x256 bf16) ----------------
__global__ void k_prepw1(const float* __restrict__ W1, u16* __restrict__ W1T) {
    int idx = blockIdx.x * blockDim.x + threadIdx.x;   // 0..32767
    if (idx >= HDIM * F_IN) return;
    int f = idx >> 8;         // 0..127
    int k = idx & 255;        // 0..255
    W1T[idx] = f2bf(W1[(size_t)k * HDIM + f]);
}

// ---------------- K3: T1 = x @ W1 via bf16 MFMA, W1T staged in LDS ----------
// Block = 8 waves x 32 rows = 256 rows. Full W1T (64 KB bf16) in LDS,
// XOR-swizzled (byte ^= (row&7)<<4). 2 blocks/CU -> 16 waves/CU = 4/SIMD.
// A-frag converted fp32->bf16 via v_cvt_pk_bf16_f32 (2 per instr).
// D: col = lane&15, row = (lane>>4)*4 + reg   [m89-verified]
__global__ __launch_bounds__(512, 4) void k_gemm1(const float* __restrict__ x,
                                                  const u16* __restrict__ W1T,
                                                  u16* __restrict__ T1, int n) {
    __shared__ u16 Bs[HDIM * F_IN];   // 64 KB

    int tid = threadIdx.x;
#pragma unroll
    for (int it = 0; it < 8; it++) {
        int o16 = it * 512 + tid;            // 16B-granule index 0..4095
        u32 o = (u32)o16 * 16;               // linear byte offset
        u32 swz = o ^ (((o >> 9) & 7u) << 4);
        uint4 v = ((const uint4*)W1T)[o16];
        *(uint4*)((char*)Bs + swz) = v;
    }
    __syncthreads();

    int wave = tid >> 6;
    int lane = tid & 63;
    int lr = lane & 15;
    int kg = lane >> 4;
    int r0 = blockIdx.x * 256 + wave * 32;
    if (r0 >= n) return;

    f32x4 acc[2][8];
#pragma unroll
    for (int rg = 0; rg < 2; rg++)
#pragma unroll
        for (int ct = 0; ct < 8; ct++) acc[rg][ct] = (f32x4){0.f, 0.f, 0.f, 0.f};

    int rowc[2];
#pragma unroll
    for (int rg = 0; rg < 2; rg++) {
        int row = r0 + rg * 16 + lr;
        rowc[rg] = row < n ? row : (n - 1);
    }

#pragma unroll
    for (int kk = 0; kk < F_IN / 32; kk++) {
        bf16x8 afrag[2];
#pragma unroll
        for (int rg = 0; rg < 2; rg++) {
            const float4* ap = (const float4*)(x + (size_t)rowc[rg] * F_IN + kg * 8 + kk * 32);
            float4 alo = ap[0];
            float4 ahi = ap[1];
            u32 q0 = cvtpk(alo.x, alo.y);
            u32 q1 = cvtpk(alo.z, alo.w);
            u32 q2 = cvtpk(ahi.x, ahi.y);
            u32 q3 = cvtpk(ahi.z, ahi.w);
            u32 qa[4] = {q0, q1, q2, q3};
            __builtin_memcpy(&afrag[rg], qa, 16);
        }
#pragma unroll
        for (int ct = 0; ct < 8; ct++) {
            u32 a = (u32)(ct * 16 + lr) * (F_IN * 2) + (u32)kg * 16 + (u32)kk * 64;
            u32 aswz = a ^ (((a >> 9) & 7u) << 4);
            bf16x8 bfrag = *(const bf16x8*)((const char*)Bs + aswz);
#pragma unroll
            for (int rg = 0; rg < 2; rg++)
                acc[rg][ct] = __builtin_amdgcn_mfma_f32_16x16x32_bf16(afrag[rg], bfrag, acc[rg][ct], 0, 0, 0);
        }
    }

    // store: T1[r0 + rg*16 + kg*4 + i][ct*16 + lr]
#pragma unroll
    for (int rg = 0; rg < 2; rg++) {
        int rbase = r0 + rg * 16 + kg * 4;
#pragma unroll
        for (int ct = 0; ct < 8; ct++) {
#pragma unroll
            for (int i = 0; i < 4; i += 2) {
                u32 q = cvtpk(acc[rg][ct][i], acc[rg][ct][i + 1]);
                int row0 = rbase + i;
                int row1 = rbase + i + 1;
                if (row0 < n) T1[(size_t)row0 * HDIM + ct * 16 + lr] = (u16)(q & 0xFFFFu);
                if (row1 < n) T1[(size_t)row1 * HDIM + ct * 16 + lr] = (u16)(q >> 16);
            }
        }
    }
}

// ---------------- K4: H = relu(SpMM(T1) + b1)  (bf16 in/out) ----------------
// 4 waves/block, 1 row/wave. Wave = 4x 16-lane subgroups, each owns one edge.
// Lane gathers 16B (8 bf16 features). Unroll x4 -> 16 outstanding gathers/wave.
__global__ __launch_bounds__(256) void k_spmm1(const u16* __restrict__ T1,
                                               const float* __restrict__ wn,
                                               const int* __restrict__ rowptr,
                                               const int* __restrict__ col,
                                               const float* __restrict__ b1,
                                               u16* __restrict__ H, int n) {
    int wave = threadIdx.x >> 6;
    int lane = threadIdx.x & 63;
    int r = blockIdx.x * 4 + wave;
    if (r >= n) return;
    int es = lane >> 4;          // subgroup 0..3 (edge slot)
    int fl = lane & 15;          // feature group: features fl*8 .. fl*8+7

    int s = rowptr[r], e = rowptr[r + 1];
    float a[8];
#pragma unroll
    for (int j = 0; j < 8; j++) a[j] = 0.f;

#define ACCUM(w_, p_) do { \
        a[0] += (w_) * bf2f((p_).x & 0xFFFFu); a[1] += (w_) * bf2f((p_).x >> 16); \
        a[2] += (w_) * bf2f((p_).y & 0xFFFFu); a[3] += (w_) * bf2f((p_).y >> 16); \
        a[4] += (w_) * bf2f((p_).z & 0xFFFFu); a[5] += (w_) * bf2f((p_).z >> 16); \
        a[6] += (w_) * bf2f((p_).w & 0xFFFFu); a[7] += (w_) * bf2f((p_).w >> 16); \
    } while (0)

    int i = s + es;
    for (; i + 12 < e; i += 16) {
        float w0 = wn[i];      int c0 = col[i];
        float w1 = wn[i + 4];  int c1 = col[i + 4];
        float w2 = wn[i + 8];  int c2 = col[i + 8];
        float w3 = wn[i + 12]; int c3 = col[i + 12];
        uint4 p0 = *(const uint4*)(T1 + (size_t)c0 * HDIM + fl * 8);
        uint4 p1 = *(const uint4*)(T1 + (size_t)c1 * HDIM + fl * 8);
        uint4 p2 = *(const uint4*)(T1 + (size_t)c2 * HDIM + fl * 8);
        uint4 p3 = *(const uint4*)(T1 + (size_t)c3 * HDIM + fl * 8);
        ACCUM(w0, p0);
        ACCUM(w1, p1);
        ACCUM(w2, p2);
        ACCUM(w3, p3);
    }
    for (; i < e; i += 4) {
        float w0 = wn[i];
        int c0 = col[i];
        uint4 p0 = *(const uint4*)(T1 + (size_t)c0 * HDIM + fl * 8);
        ACCUM(w0, p0);
    }
#undef ACCUM

    // reduce across the 4 edge subgroups
#pragma unroll
    for (int j = 0; j < 8; j++) {
        a[j] += __shfl_xor(a[j], 16);
        a[j] += __shfl_xor(a[j], 32);
    }

    if (es == 0) {
        const float4* bb = (const float4*)(b1 + fl * 8);
        float4 blo = bb[0], bhi = bb[1];
        float v0 = a[0] + blo.x, v1 = a[1] + blo.y;
        float v2 = a[2] + blo.z, v3 = a[3] + blo.w;
        float v4 = a[4] + bhi.x, v5 = a[5] + bhi.y;
        float v6 = a[6] + bhi.z, v7 = a[7] + bhi.w;
        v0 = v0 > 0.f ? v0 : 0.f; v1 = v1 > 0.f ? v1 : 0.f;
        v2 = v2 > 0.f ? v2 : 0.f; v3 = v3 > 0.f ? v3 : 0.f;
        v4 = v4 > 0.f ? v4 : 0.f; v5 = v5 > 0.f ? v5 : 0.f;
        v6 = v6 > 0.f ? v6 : 0.f; v7 = v7 > 0.f ? v7 : 0.f;
        uint4 o;
        o.x = cvtpk(v0, v1); o.y = cvtpk(v2, v3);
        o.z = cvtpk(v4, v5); o.w = cvtpk(v6, v7);
        *(uint4*)(H + (size_t)r * HDIM + fl * 8) = o;
    }
}

// ---------------- K5: U = H @ W2  (bf16 in, f32 out) ----------------
__global__ __launch_bounds__(256) void k_gemm2(const u16* __restrict__ H,
                                               const float* __restrict__ W2,
                                               float* __restrict__ U, int n) {
    int rl = threadIdx.x >> 4;
    int f = threadIdx.x & 15;
    int row = blockIdx.x * 16 + rl;
    if (row >= n) return;
    const u32* hr = (const u32*)(H + (size_t)row * HDIM);
    float acc = 0.f;
    for (int k2 = 0; k2 < HDIM / 2; k2++) {
        u32 pr = hr[k2];
        float h0 = bf2f(pr & 0xFFFFu);
        float h1 = bf2f(pr >> 16);
        acc += h0 * W2[(size_t)(k2 * 2) * CDIM + f];
        acc += h1 * W2[(size_t)(k2 * 2 + 1) * CDIM + f];
    }
    U[(size_t)row * CDIM + f] = acc;
}

// ---------------- K6: out = log_softmax(SpMM(U) + b2) ----------------
// 4 waves/block, 1 row/wave: 8 edge-subgroups x 8 lanes (float2/lane), x2 unroll
// -> 16 outstanding 8B-gathers per wave.
__global__ __launch_bounds__(256) void k_out(const float* __restrict__ U,
                                             const float* __restrict__ wn,
                                             const int* __restrict__ rowptr,
                                             const int* __restrict__ col,
                                             const float* __restrict__ b2,
                                             float* __restrict__ out, int n) {
    int wave = threadIdx.x >> 6;
    int lane = threadIdx.x & 63;
    int r = blockIdx.x * 4 + wave;
    if (r >= n) return;
    int es = lane >> 3;   // 0..7 edge slot
    int fl = lane & 7;    // feature pair: 2*fl, 2*fl+1
    int s = rowptr[r], e = rowptr[r + 1];
    float a0 = 0.f, a1 = 0.f;

    int i = s + es;
    for (; i + 8 < e; i += 16) {
        float w0 = wn[i];     int c0 = col[i];
        float w1 = wn[i + 8]; int c1 = col[i + 8];
        float2 u0 = *(const float2*)(U + (size_t)c0 * CDIM + fl * 2);
        float2 u1 = *(const float2*)(U + (size_t)c1 * CDIM + fl * 2);
        a0 += w0 * u0.x; a1 += w0 * u0.y;
        a0 += w1 * u1.x; a1 += w1 * u1.y;
    }
    for (; i < e; i += 8) {
        float w0 = wn[i];
        int c0 = col[i];
        float2 u0 = *(const float2*)(U + (size_t)c0 * CDIM + fl * 2);
        a0 += w0 * u0.x; a1 += w0 * u0.y;
    }

    // reduce across the 8 edge sub-groups (lanes differing in bits 3..5)
    a0 += __shfl_xor(a0, 8);  a1 += __shfl_xor(a1, 8);
    a0 += __shfl_xor(a0, 16); a1 += __shfl_xor(a1, 16);
    a0 += __shfl_xor(a0, 32); a1 += __shfl_xor(a1, 32);

    float2 bp = ((const float2*)b2)[fl];
    float v0 = a0 + bp.x;
    float v1 = a1 + bp.y;

    // log-softmax over 16 classes spread across 8 lanes x 2
    float m = fmaxf(v0, v1);
    m = fmaxf(m, __shfl_xor(m, 1));
    m = fmaxf(m, __shfl_xor(m, 2));
    m = fmaxf(m, __shfl_xor(m, 4));
    float ss = __expf(v0 - m) + __expf(v1 - m);
    ss += __shfl_xor(ss, 1);
    ss += __shfl_xor(ss, 2);
    ss += __shfl_xor(ss, 4);
    float ls = __logf(ss);
    if (es == 0) {
        float2 res = {v0 - m - ls, v1 - m - ls};
        *(float2*)(out + (size_t)r * CDIM + fl * 2) = res;
    }
}

extern "C" void kernel_launch(void* const* d_in, const int* in_sizes, int n_in,
                              void* d_out, int out_size, void* d_ws, size_t ws_size,
                              hipStream_t stream) {
    const float* x      = (const float*)d_in[0];
    const float* ew     = (const float*)d_in[1];
    const float* W1     = (const float*)d_in[2];
    const float* b1     = (const float*)d_in[3];
    const float* W2     = (const float*)d_in[4];
    const float* b2     = (const float*)d_in[5];
    const int*   rowptr = (const int*)d_in[6];
    const int*   colind = (const int*)d_in[7];

    int n = in_sizes[6] - 1;   // rowptr has n+1 entries
    int E = in_sizes[7];

    auto align256 = [](size_t v) { return (v + 255) & ~(size_t)255; };
    char* p = (char*)d_ws;
    float* dinv = (float*)p; p += align256((size_t)n * 4);
    float* wn   = (float*)p; p += align256((size_t)E * 4);
    u16*   T1   = (u16*)p;   p += align256((size_t)n * HDIM * 2);
    u16*   H    = (u16*)p;   p += align256((size_t)n * HDIM * 2);
    float* U    = (float*)p; p += align256((size_t)n * CDIM * 4);
    u16*   W1T  = (u16*)p;   p += align256((size_t)HDIM * F_IN * 2);
    float* out  = (float*)d_out;

    k_dinv<<<(n + 255) / 256, 256, 0, stream>>>(ew, rowptr, dinv, n);
    k_w<<<(n + 255) / 256, 256, 0, stream>>>(ew, rowptr, colind, dinv, wn, n);
    k_prepw1<<<(HDIM * F_IN + 255) / 256, 256, 0, stream>>>(W1, W1T);

    k_gemm1<<<(n + 255) / 256, 512, 0, stream>>>(x, W1T, T1, n);

    k_spmm1<<<(n + 3) / 4, 256, 0, stream>>>(T1, wn, rowptr, colind, b1, H, n);
    k_gemm2<<<(n + 15) / 16, 256, 0, stream>>>(H, W2, U, n);
    k_out<<<(n + 3) / 4, 256, 0, stream>>>(U, wn, rowptr, colind, b2, out, n);
}